// Round 1
// baseline (774.202 us; speedup 1.0000x reference)
//
#include <hip/hip_runtime.h>

typedef unsigned short u16;
typedef unsigned int   u32;
typedef short bf16x8 __attribute__((ext_vector_type(8)));
typedef float f32x4  __attribute__((ext_vector_type(4)));

#define KT 5824   // 5760 (x_q) + 32 (t) + 32 (zero pad)
#define KI 91     // KT / 64

__device__ __forceinline__ u16 bf16_rtne(float f) {
  u32 u = __builtin_bit_cast(u32, f);
  u += 0x7fffu + ((u >> 16) & 1u);
  return (u16)(u >> 16);
}

__device__ __forceinline__ void load_lds16(const void* g, void* s) {
  __builtin_amdgcn_global_load_lds((const __attribute__((address_space(1))) void*)g,
                                   (__attribute__((address_space(3))) void*)s,
                                   16, 0, 0);
}

// ---------------------------------------------------------------------------
// Weight prep: Bt[n][k] = (k<5760 ? qweight[k][n]*wscales[k/64][n]
//                          : k<5792 ? proj_up[k-5760][n] : 0), bf16, k-contig.
// Tiled 64x64 transpose through LDS (stride 66 to break bank conflicts).
// ---------------------------------------------------------------------------
__global__ __launch_bounds__(256) void wprep(const float* __restrict__ qw,
                                             const float* __restrict__ wsc,
                                             const float* __restrict__ pu,
                                             u16* __restrict__ Bt) {
  __shared__ u16 tile[64 * 66];
  const int tid = threadIdx.x;
  const int k0 = blockIdx.x * 64, n0 = blockIdx.y * 64;
  {
    const int n = tid & 63, kk = tid >> 6;
    const float wv = (k0 < 5760) ? wsc[(size_t)(k0 >> 6) * 640 + n0 + n] : 0.f;
    for (int p = 0; p < 16; ++p) {
      const int k = p * 4 + kk;
      const int gk = k0 + k;
      float v;
      if (gk < 5760)      v = qw[(size_t)gk * 640 + n0 + n] * wv;
      else if (gk < 5792) v = pu[(size_t)(gk - 5760) * 640 + n0 + n];
      else                v = 0.f;
      tile[k * 66 + n] = bf16_rtne(v);
    }
  }
  __syncthreads();
  {
    const int k = tid & 63, nn = tid >> 6;
    for (int p = 0; p < 16; ++p) {
      const int n2 = p * 4 + nn;
      Bt[(size_t)(n0 + n2) * KT + k0 + k] = tile[k * 66 + n2];
    }
  }
}

// ---------------------------------------------------------------------------
// pd prep: pack proj_down (5760x32 f32) into per-group MFMA B-operand
// fragments, bf16. frag f = kc*2+nt: lane l, elem j ->
//   pd[g*64 + kc*32 + (l>>4)*8 + j][nt*16 + (l&15)]
// ---------------------------------------------------------------------------
__global__ __launch_bounds__(256) void pdprep(const float* __restrict__ pd,
                                              u16* __restrict__ pdp) {
  const int g = blockIdx.x;
  const int f = threadIdx.x >> 6, l = threadIdx.x & 63;
  const int kc = f >> 1, nt = f & 1;
  const int k = g * 64 + kc * 32 + ((l >> 4) * 8);
  const int r = nt * 16 + (l & 15);
  u32 w[4];
  for (int jj = 0; jj < 4; ++jj) {
    u16 a = bf16_rtne(pd[(size_t)(k + 2 * jj) * 32 + r]);
    u16 b = bf16_rtne(pd[(size_t)(k + 2 * jj + 1) * 32 + r]);
    w[jj] = (u32)a | ((u32)b << 16);
  }
  *(uint4*)(pdp + ((size_t)(g * 4 + f) * 64 + l) * 8) = make_uint4(w[0], w[1], w[2], w[3]);
}

// ---------------------------------------------------------------------------
// Activation prep. Block = 16 rows x 256 thr (4 waves, K split 23/23/22/22
// groups). Per group: load x f32, group absmax -> scale, fake-quant -> bf16
// into A[:, 0..5759]; raw-x bf16 via LDS -> MFMA accumulate t = x@pd;
// at end reduce 4 partial t's, write A[:, 5760..5791]=t, A[:, 5792..5823]=0.
// ---------------------------------------------------------------------------
__device__ __forceinline__ void quant4(const float4 v, float inv, float s,
                                       u16* gq, u16* lraw) {
  float qx = fminf(fmaxf(rintf(v.x * inv), -8.f), 7.f);
  float qy = fminf(fmaxf(rintf(v.y * inv), -8.f), 7.f);
  float qz = fminf(fmaxf(rintf(v.z * inv), -8.f), 7.f);
  float qw = fminf(fmaxf(rintf(v.w * inv), -8.f), 7.f);
  ushort4 dq;
  dq.x = bf16_rtne(qx * s); dq.y = bf16_rtne(qy * s);
  dq.z = bf16_rtne(qz * s); dq.w = bf16_rtne(qw * s);
  *(ushort4*)gq = dq;
  ushort4 rw;
  rw.x = bf16_rtne(v.x); rw.y = bf16_rtne(v.y);
  rw.z = bf16_rtne(v.z); rw.w = bf16_rtne(v.w);
  *(ushort4*)lraw = rw;
}

__global__ __launch_bounds__(256) void prep(const float* __restrict__ x,
                                            const u16* __restrict__ pdp,
                                            u16* __restrict__ A) {
  __shared__ u16 xt[4][16 * 72];   // per-wave raw-x bf16 tile, row stride 72
  __shared__ float tl[4][512];     // per-wave partial t (16x32)
  const int tid = threadIdx.x;
  const int lane = tid & 63;
  const int w = tid >> 6;
  const int m0 = blockIdx.x * 16;
  const int row = lane >> 2, cq = lane & 3;
  const float* xrow = x + (size_t)(m0 + row) * 5760;
  u16* arow = A + (size_t)(m0 + row) * KT;
  u16* xts = &xt[w][row * 72 + cq * 4];
  const int frow = lane & 15, fq = lane >> 4;
  const u16* xfr = &xt[w][frow * 72 + fq * 8];
  const int g0 = (w < 2) ? w * 23 : 46 + (w - 2) * 22;
  const int gcnt = (w < 2) ? 23 : 22;
  f32x4 tacc[2] = {};
  for (int gi = 0; gi < gcnt; ++gi) {
    const int g = g0 + gi;
    const float* px = xrow + g * 64 + cq * 4;
    float4 v0 = *(const float4*)(px);
    float4 v1 = *(const float4*)(px + 16);
    float4 v2 = *(const float4*)(px + 32);
    float4 v3 = *(const float4*)(px + 48);
    float mx = fmaxf(fabsf(v0.x), fabsf(v0.y));
    mx = fmaxf(mx, fabsf(v0.z)); mx = fmaxf(mx, fabsf(v0.w));
    mx = fmaxf(mx, fabsf(v1.x)); mx = fmaxf(mx, fabsf(v1.y));
    mx = fmaxf(mx, fabsf(v1.z)); mx = fmaxf(mx, fabsf(v1.w));
    mx = fmaxf(mx, fabsf(v2.x)); mx = fmaxf(mx, fabsf(v2.y));
    mx = fmaxf(mx, fabsf(v2.z)); mx = fmaxf(mx, fabsf(v2.w));
    mx = fmaxf(mx, fabsf(v3.x)); mx = fmaxf(mx, fabsf(v3.y));
    mx = fmaxf(mx, fabsf(v3.z)); mx = fmaxf(mx, fabsf(v3.w));
    mx = fmaxf(mx, __shfl_xor(mx, 1, 64));
    mx = fmaxf(mx, __shfl_xor(mx, 2, 64));
    const float s = fmaxf(mx / 7.0f, 1e-6f);
    const float inv = 1.0f / s;
    u16* ar = arow + g * 64 + cq * 4;
    quant4(v0, inv, s, ar,      xts);
    quant4(v1, inv, s, ar + 16, xts + 16);
    quant4(v2, inv, s, ar + 32, xts + 32);
    quant4(v3, inv, s, ar + 48, xts + 48);
    // t accumulation: D[m][r] += x_raw(16xK) @ pd(Kx32)
#pragma unroll
    for (int kc = 0; kc < 2; ++kc) {
      bf16x8 xf = *(const bf16x8*)(xfr + kc * 32);
#pragma unroll
      for (int nt = 0; nt < 2; ++nt) {
        bf16x8 pf = *(const bf16x8*)(pdp + ((size_t)(g * 4 + kc * 2 + nt) * 64 + lane) * 8);
        tacc[nt] = __builtin_amdgcn_mfma_f32_16x16x32_bf16(xf, pf, tacc[nt], 0, 0, 0);
      }
    }
  }
#pragma unroll
  for (int nt = 0; nt < 2; ++nt)
#pragma unroll
    for (int r0 = 0; r0 < 4; ++r0)
      tl[w][(fq * 4 + r0) * 32 + nt * 16 + frow] = tacc[nt][r0];
  __syncthreads();
  if (w == 0) {   // sum 4 partials, write t into A[:, 5760..5791]
    const int m = lane >> 2, rb = (lane & 3) * 8;
    u32 pk[4];
    for (int jj = 0; jj < 4; ++jj) {
      const int i0 = m * 32 + rb + 2 * jj;
      float sa = tl[0][i0] + tl[1][i0] + tl[2][i0] + tl[3][i0];
      float sb = tl[0][i0 + 1] + tl[1][i0 + 1] + tl[2][i0 + 1] + tl[3][i0 + 1];
      pk[jj] = (u32)bf16_rtne(sa) | ((u32)bf16_rtne(sb) << 16);
    }
    *(uint4*)(A + (size_t)(m0 + m) * KT + 5760 + rb) = make_uint4(pk[0], pk[1], pk[2], pk[3]);
  } else if (w == 1) {  // zero pad A[:, 5792..5823]
    const int m = lane >> 2, rb = (lane & 3) * 8;
    *(uint4*)(A + (size_t)(m0 + m) * KT + 5792 + rb) = make_uint4(0, 0, 0, 0);
  }
}

// ---------------------------------------------------------------------------
// Main GEMM: C[m][n] = A[m][:]·Bt[n][:], 128x128 tile, BK=64, bf16 MFMA.
// Both tiles staged with global_load_lds (16B) using XOR chunk swizzle:
// LDS[r][slot] = global chunk (slot ^ (r&7)) -> conflict-free ds_read_b128.
// Operand-swapped mfma => C/D has m in lane&15 => coalesced transposed store
// out[batch][c][l] (+bias).
// ---------------------------------------------------------------------------
__global__ __launch_bounds__(256, 3) void gemm_kernel(const u16* __restrict__ A,
                                                      const u16* __restrict__ Bt,
                                                      const float* __restrict__ bias,
                                                      float* __restrict__ out) {
  __shared__ u16 As[128 * 64];
  __shared__ u16 Bs[128 * 64];
  const int tid = threadIdx.x;
  const int lane = tid & 63;
  const int w = tid >> 6;
  const int wm = w & 1, wn = w >> 1;
  const int m0 = blockIdx.y * 128;
  const int n0 = blockIdx.x * 128;

  const int srow = lane >> 3;           // 0..7 within 8-row staging group
  const int sch = (lane & 7) ^ srow;    // swizzled source chunk
  const u16* ga = A  + (size_t)(m0 + w * 32 + srow) * KT + sch * 8;
  const u16* gb = Bt + (size_t)(n0 + w * 32 + srow) * KT + sch * 8;

  const int frow = lane & 15, fq = lane >> 4;
  const int a0 = (wm * 64 + frow) * 64 + ((fq       ^ (frow & 7)) * 8);
  const int a1 = (wm * 64 + frow) * 64 + (((fq + 4) ^ (frow & 7)) * 8);
  const int b0 = (wn * 64 + frow) * 64 + ((fq       ^ (frow & 7)) * 8);
  const int b1 = (wn * 64 + frow) * 64 + (((fq + 4) ^ (frow & 7)) * 8);

  f32x4 acc[4][4] = {};

  for (int kt = 0; kt < KI; ++kt) {
    const u16* gak = ga + kt * 64;
    const u16* gbk = gb + kt * 64;
#pragma unroll
    for (int i = 0; i < 4; ++i) {
      load_lds16(gak + (size_t)(i * 8) * KT, &As[(w * 32 + i * 8) * 64]);
      load_lds16(gbk + (size_t)(i * 8) * KT, &Bs[(w * 32 + i * 8) * 64]);
    }
    __syncthreads();
#pragma unroll
    for (int kc = 0; kc < 2; ++kc) {
      const int ab = kc ? a1 : a0;
      const int bb = kc ? b1 : b0;
      bf16x8 af[4], bfr[4];
#pragma unroll
      for (int t = 0; t < 4; ++t) af[t] = *(const bf16x8*)&As[ab + t * 1024];
#pragma unroll
      for (int t = 0; t < 4; ++t) bfr[t] = *(const bf16x8*)&Bs[bb + t * 1024];
#pragma unroll
      for (int mt = 0; mt < 4; ++mt)
#pragma unroll
        for (int nt = 0; nt < 4; ++nt)
          acc[mt][nt] = __builtin_amdgcn_mfma_f32_16x16x32_bf16(bfr[nt], af[mt], acc[mt][nt], 0, 0, 0);
    }
    __syncthreads();
  }

  // Epilogue: c = row index of D (fq*4+reg), m = col index (frow).
  const int batch = m0 >> 12;
  float* outb = out + (size_t)batch * (640 * 4096) + (m0 & 4095) + wm * 64 + frow;
  const int cb = n0 + wn * 64 + fq * 4;
#pragma unroll
  for (int nt = 0; nt < 4; ++nt) {
#pragma unroll
    for (int r = 0; r < 4; ++r) {
      const int c = cb + nt * 16 + r;
      const float bv = bias[c];
      float* op = outb + (size_t)c * 4096;
#pragma unroll
      for (int mt = 0; mt < 4; ++mt)
        op[mt * 16] = acc[mt][nt][r] + bv;
    }
  }
}

// ---------------------------------------------------------------------------
// ws layout: A   @ 0         : 16384*5824*2 = 190,840,832 B
//            Bt  @ 190840832 :   640*5824*2 =   7,454,720 B
//            pdp @ 198295552 : 90*4*64*16   =     368,640 B   (total 198.7 MB)
// ---------------------------------------------------------------------------
extern "C" void kernel_launch(void* const* d_in, const int* in_sizes, int n_in,
                              void* d_out, int out_size, void* d_ws, size_t ws_size,
                              hipStream_t stream) {
  const float* x    = (const float*)d_in[0];
  const float* qw   = (const float*)d_in[1];
  const float* wsc  = (const float*)d_in[2];
  const float* pd   = (const float*)d_in[3];
  const float* pu   = (const float*)d_in[4];
  const float* bias = (const float*)d_in[5];
  float* out = (float*)d_out;
  char* wsb = (char*)d_ws;
  u16* A   = (u16*)wsb;
  u16* Bt  = (u16*)(wsb + 190840832);
  u16* pdp = (u16*)(wsb + 198295552);

  wprep<<<dim3(91, 10), dim3(256), 0, stream>>>(qw, wsc, pu, Bt);
  pdprep<<<dim3(90), dim3(256), 0, stream>>>(pd, pdp);
  prep<<<dim3(1024), dim3(256), 0, stream>>>(x, pdp, A);
  gemm_kernel<<<dim3(5, 128), dim3(256), 0, stream>>>(A, Bt, bias, out);
}

// Round 2
// 722.156 us; speedup vs baseline: 1.0721x; 1.0721x over previous
//
#include <hip/hip_runtime.h>

typedef unsigned short u16;
typedef unsigned int   u32;
typedef short bf16x8 __attribute__((ext_vector_type(8)));
typedef float f32x4  __attribute__((ext_vector_type(4)));

#define KT 5824   // 5760 (x_q) + 32 (t) + 32 (zero pad)
#define KI 91     // KT / 64

__device__ __forceinline__ u16 bf16_rtne(float f) {
  u32 u = __builtin_bit_cast(u32, f);
  u += 0x7fffu + ((u >> 16) & 1u);
  return (u16)(u >> 16);
}

__device__ __forceinline__ u32 pack2(float a, float b) {
  return (u32)bf16_rtne(a) | ((u32)bf16_rtne(b) << 16);
}

__device__ __forceinline__ float fq1(float v, float inv, float s) {
  return fminf(fmaxf(rintf(v * inv), -8.f), 7.f) * s;
}

__device__ __forceinline__ void load_lds16(const void* g, void* s) {
  __builtin_amdgcn_global_load_lds((const __attribute__((address_space(1))) void*)g,
                                   (__attribute__((address_space(3))) void*)s,
                                   16, 0, 0);
}

// ---------------------------------------------------------------------------
// Weight prep: Bt[n][k] = (k<5760 ? qweight[k][n]*wscales[k/64][n]
//                          : k<5792 ? proj_up[k-5760][n] : 0), bf16, k-contig.
// ---------------------------------------------------------------------------
__global__ __launch_bounds__(256) void wprep(const float* __restrict__ qw,
                                             const float* __restrict__ wsc,
                                             const float* __restrict__ pu,
                                             u16* __restrict__ Bt) {
  __shared__ u16 tile[64 * 66];
  const int tid = threadIdx.x;
  const int k0 = blockIdx.x * 64, n0 = blockIdx.y * 64;
  {
    const int n = tid & 63, kk = tid >> 6;
    const float wv = (k0 < 5760) ? wsc[(size_t)(k0 >> 6) * 640 + n0 + n] : 0.f;
    for (int p = 0; p < 16; ++p) {
      const int k = p * 4 + kk;
      const int gk = k0 + k;
      float v;
      if (gk < 5760)      v = qw[(size_t)gk * 640 + n0 + n] * wv;
      else if (gk < 5792) v = pu[(size_t)(gk - 5760) * 640 + n0 + n];
      else                v = 0.f;
      tile[k * 66 + n] = bf16_rtne(v);
    }
  }
  __syncthreads();
  {
    const int k = tid & 63, nn = tid >> 6;
    for (int p = 0; p < 16; ++p) {
      const int n2 = p * 4 + nn;
      Bt[(size_t)(n0 + n2) * KT + k0 + k] = tile[k * 66 + n2];
    }
  }
}

// ---------------------------------------------------------------------------
// pd prep: pack proj_down (5760x32 f32) into per-group MFMA B-operand frags.
// ---------------------------------------------------------------------------
__global__ __launch_bounds__(256) void pdprep(const float* __restrict__ pd,
                                              u16* __restrict__ pdp) {
  const int g = blockIdx.x;
  const int f = threadIdx.x >> 6, l = threadIdx.x & 63;
  const int kc = f >> 1, nt = f & 1;
  const int k = g * 64 + kc * 32 + ((l >> 4) * 8);
  const int r = nt * 16 + (l & 15);
  u32 w[4];
  for (int jj = 0; jj < 4; ++jj)
    w[jj] = pack2(pd[(size_t)(k + 2 * jj) * 32 + r], pd[(size_t)(k + 2 * jj + 1) * 32 + r]);
  *(uint4*)(pdp + ((size_t)(g * 4 + f) * 64 + l) * 8) = make_uint4(w[0], w[1], w[2], w[3]);
}

// ---------------------------------------------------------------------------
// Activation prep. Block = 16 rows x 4 waves; wave owns a contiguous group
// range {23,22,22,23}. Per group (64 cols): 2 passes of 8 rows; lane = 8 lanes
// per row x 8 cols -> float4 x2 loads, uint4 (128-B segment) quant stores.
// Raw bf16 -> chunk-XOR-swizzled 16x64 LDS tile -> MFMA t += x@pd.
// ---------------------------------------------------------------------------
__global__ __launch_bounds__(256) void prep(const float* __restrict__ x,
                                            const u16* __restrict__ pdp,
                                            u16* __restrict__ A) {
  __shared__ u16 xt[4][16 * 64];   // per-wave raw-x bf16, chunk-swizzled
  __shared__ float tl[4][512];     // per-wave partial t (16x32)
  const int tid = threadIdx.x;
  const int lane = tid & 63;
  const int w = tid >> 6;
  const int m0 = blockIdx.x * 16;
  const int r8 = lane >> 3, c8 = lane & 7;
  const int frow = lane & 15, fq = lane >> 4;
  const int g0   = (w == 0) ? 0 : (w == 1) ? 23 : (w == 2) ? 45 : 67;
  const int gcnt = (w == 0 || w == 3) ? 23 : 22;
  u16* xts = &xt[w][0];
  f32x4 tacc[2] = {};
  for (int gi = 0; gi < gcnt; ++gi) {
    const int g = g0 + gi;
#pragma unroll
    for (int pass = 0; pass < 2; ++pass) {
      const int row = pass * 8 + r8;
      const float* px = x + (size_t)(m0 + row) * 5760 + g * 64 + c8 * 8;
      float4 v0 = *(const float4*)px;
      float4 v1 = *(const float4*)(px + 4);
      float mx = fmaxf(fmaxf(fmaxf(fabsf(v0.x), fabsf(v0.y)), fmaxf(fabsf(v0.z), fabsf(v0.w))),
                       fmaxf(fmaxf(fabsf(v1.x), fabsf(v1.y)), fmaxf(fabsf(v1.z), fabsf(v1.w))));
      mx = fmaxf(mx, __shfl_xor(mx, 1, 64));
      mx = fmaxf(mx, __shfl_xor(mx, 2, 64));
      mx = fmaxf(mx, __shfl_xor(mx, 4, 64));
      const float s = fmaxf(mx / 7.0f, 1e-6f);
      const float inv = 1.0f / s;
      // quantized A write: 8 lanes x 16 B = 128-B contiguous segment per row
      uint4 qv = make_uint4(pack2(fq1(v0.x, inv, s), fq1(v0.y, inv, s)),
                            pack2(fq1(v0.z, inv, s), fq1(v0.w, inv, s)),
                            pack2(fq1(v1.x, inv, s), fq1(v1.y, inv, s)),
                            pack2(fq1(v1.z, inv, s), fq1(v1.w, inv, s)));
      *(uint4*)(A + (size_t)(m0 + row) * KT + g * 64 + c8 * 8) = qv;
      // raw bf16 -> LDS, chunk slot = c8 ^ (row&7)  (row&7 == r8)
      uint4 rv = make_uint4(pack2(v0.x, v0.y), pack2(v0.z, v0.w),
                            pack2(v1.x, v1.y), pack2(v1.z, v1.w));
      *(uint4*)(&xts[row * 64 + ((c8 ^ r8) * 8)]) = rv;
    }
    // t accumulation: D += x_raw(16xK) @ pd(Kx32)
#pragma unroll
    for (int kc = 0; kc < 2; ++kc) {
      bf16x8 xf = *(const bf16x8*)&xts[frow * 64 + (((kc * 4 + fq) ^ (frow & 7)) * 8)];
#pragma unroll
      for (int nt = 0; nt < 2; ++nt) {
        bf16x8 pf = *(const bf16x8*)(pdp + ((size_t)(g * 4 + kc * 2 + nt) * 64 + lane) * 8);
        tacc[nt] = __builtin_amdgcn_mfma_f32_16x16x32_bf16(xf, pf, tacc[nt], 0, 0, 0);
      }
    }
  }
#pragma unroll
  for (int nt = 0; nt < 2; ++nt)
#pragma unroll
    for (int r0 = 0; r0 < 4; ++r0)
      tl[w][(fq * 4 + r0) * 32 + nt * 16 + frow] = tacc[nt][r0];
  __syncthreads();
  if (w == 0) {   // sum 4 partials, write t into A[:, 5760..5791]
    const int m = lane >> 2, rb = (lane & 3) * 8;
    u32 pk[4];
    for (int jj = 0; jj < 4; ++jj) {
      const int i0 = m * 32 + rb + 2 * jj;
      float sa = tl[0][i0] + tl[1][i0] + tl[2][i0] + tl[3][i0];
      float sb = tl[0][i0 + 1] + tl[1][i0 + 1] + tl[2][i0 + 1] + tl[3][i0 + 1];
      pk[jj] = (u32)bf16_rtne(sa) | ((u32)bf16_rtne(sb) << 16);
    }
    *(uint4*)(A + (size_t)(m0 + m) * KT + 5760 + rb) = make_uint4(pk[0], pk[1], pk[2], pk[3]);
  } else if (w == 1) {  // zero pad A[:, 5792..5823]
    const int m = lane >> 2, rb = (lane & 3) * 8;
    *(uint4*)(A + (size_t)(m0 + m) * KT + 5792 + rb) = make_uint4(0, 0, 0, 0);
  }
}

// ---------------------------------------------------------------------------
// Main GEMM: 128(m) x 160(n) tile, BK=64, bf16 MFMA, 512 blocks = 2/CU even.
// XCD-aware remap (lin&7 = XCD): n-major order so each XCD serves half of one
// n-tile -> its 1.86 MB B slice stays L2-resident. XOR chunk swizzle in the
// global_load_lds source keeps ds_read_b128 conflict-free. Operand-swapped
// MFMA -> m in lane&15 -> coalesced transposed store.
// ---------------------------------------------------------------------------
__global__ __launch_bounds__(256, 2) void gemm_kernel(const u16* __restrict__ A,
                                                      const u16* __restrict__ Bt,
                                                      const float* __restrict__ bias,
                                                      float* __restrict__ out) {
  __shared__ u16 As[128 * 64];
  __shared__ u16 Bs[160 * 64];
  const int tid = threadIdx.x;
  const int lane = tid & 63;
  const int w = tid >> 6;
  const int wm = w & 1, wn = w >> 1;
  const int lin = blockIdx.x;
  const int g = (lin & 7) * 64 + (lin >> 3);   // XCD-pinned n-major order
  const int n0 = (g >> 7) * 160;
  const int m0 = (g & 127) * 128;

  const int srow = lane >> 3;           // 0..7 within 8-row staging group
  const int sch = (lane & 7) ^ srow;    // swizzled source chunk
  const u16* ga = A  + (size_t)(m0 + w * 32 + srow) * KT + sch * 8;
  const u16* gb = Bt + (size_t)(n0 + w * 40 + srow) * KT + sch * 8;

  const int frow = lane & 15, fq = lane >> 4;
  f32x4 acc[4][5] = {};

  for (int kt = 0; kt < KI; ++kt) {
    const u16* gak = ga + kt * 64;
    const u16* gbk = gb + kt * 64;
#pragma unroll
    for (int i = 0; i < 4; ++i)
      load_lds16(gak + (size_t)(i * 8) * KT, &As[(w * 32 + i * 8) * 64]);
#pragma unroll
    for (int i = 0; i < 5; ++i)
      load_lds16(gbk + (size_t)(i * 8) * KT, &Bs[(w * 40 + i * 8) * 64]);
    __syncthreads();
#pragma unroll
    for (int kc = 0; kc < 2; ++kc) {
      const int ch = kc * 4 + fq;
      const int sw = (ch ^ (frow & 7)) * 8;
      bf16x8 af[4], bfr[5];
#pragma unroll
      for (int mt = 0; mt < 4; ++mt)
        af[mt] = *(const bf16x8*)&As[(wm * 64 + mt * 16 + frow) * 64 + sw];
#pragma unroll
      for (int nt = 0; nt < 5; ++nt)
        bfr[nt] = *(const bf16x8*)&Bs[(wn * 80 + nt * 16 + frow) * 64 + sw];
#pragma unroll
      for (int mt = 0; mt < 4; ++mt)
#pragma unroll
        for (int nt = 0; nt < 5; ++nt)
          acc[mt][nt] = __builtin_amdgcn_mfma_f32_16x16x32_bf16(bfr[nt], af[mt], acc[mt][nt], 0, 0, 0);
    }
    __syncthreads();
  }

  // Epilogue: c = n0+wn*80+nt*16+fq*4+r; m (col of D) = m0+wm*64+mt*16+frow.
  const int batch = m0 >> 12;
  float* outb = out + (size_t)batch * (640 * 4096) + (m0 & 4095) + wm * 64 + frow;
  const int cb = n0 + wn * 80 + fq * 4;
#pragma unroll
  for (int nt = 0; nt < 5; ++nt) {
#pragma unroll
    for (int r = 0; r < 4; ++r) {
      const int c = cb + nt * 16 + r;
      const float bv = bias[c];
      float* op = outb + (size_t)c * 4096;
#pragma unroll
      for (int mt = 0; mt < 4; ++mt)
        op[mt * 16] = acc[mt][nt][r] + bv;
    }
  }
}

// ---------------------------------------------------------------------------
// ws layout: A   @ 0         : 16384*5824*2 = 190,840,832 B
//            Bt  @ 190840832 :   640*5824*2 =   7,454,720 B
//            pdp @ 198295552 : 90*4*64*16   =     368,640 B   (total 198.7 MB)
// ---------------------------------------------------------------------------
extern "C" void kernel_launch(void* const* d_in, const int* in_sizes, int n_in,
                              void* d_out, int out_size, void* d_ws, size_t ws_size,
                              hipStream_t stream) {
  const float* x    = (const float*)d_in[0];
  const float* qw   = (const float*)d_in[1];
  const float* wsc  = (const float*)d_in[2];
  const float* pd   = (const float*)d_in[3];
  const float* pu   = (const float*)d_in[4];
  const float* bias = (const float*)d_in[5];
  float* out = (float*)d_out;
  char* wsb = (char*)d_ws;
  u16* A   = (u16*)wsb;
  u16* Bt  = (u16*)(wsb + 190840832);
  u16* pdp = (u16*)(wsb + 198295552);

  wprep<<<dim3(91, 10), dim3(256), 0, stream>>>(qw, wsc, pu, Bt);
  pdprep<<<dim3(90), dim3(256), 0, stream>>>(pd, pdp);
  prep<<<dim3(1024), dim3(256), 0, stream>>>(x, pdp, A);
  gemm_kernel<<<dim3(512), dim3(256), 0, stream>>>(A, Bt, bias, out);
}